// Round 1
// baseline (596.881 us; speedup 1.0000x reference)
//
#include <hip/hip_runtime.h>
#include <hip/hip_bf16.h>

typedef __bf16 bf16x8 __attribute__((ext_vector_type(8)));
typedef float  f32x4  __attribute__((ext_vector_type(4)));

#define NB 1024
#define NS 1024
#define NI 32
#define NH 128

__device__ __forceinline__ unsigned long long pack4_bf16(f32x4 v) {
  unsigned long long p = 0;
#pragma unroll
  for (int r = 0; r < 4; ++r) {
    __bf16 b = (__bf16)v[r];
    unsigned short s = __builtin_bit_cast(unsigned short, b);
    p |= (unsigned long long)s << (16 * r);
  }
  return p;
}

// Block: 256 threads = 4 waves. Each block owns 16 batch rows for the whole scan.
// Wave w computes hidden columns [32w, 32w+32).
// MFMA orientation: D'[n][m] = sum_k U[k][n] * h[m][k]  (A' = U^T slice, B' = h^T)
//  -> B'-frag: lane l holds h[m=l&15][k = 32*kt + 8*(l>>4) + j]  (8 contiguous k: one ds_read_b128)
//  -> D':     lane l holds h_new[m=l&15][n = 32w + 16mt + 4*(l>>4) + r]
// Elementwise state h_elem (fp32) stays in the D' layout per lane; bf16 copy ping-pongs in LDS.
__global__ __launch_bounds__(256, 1) void gru_scan(
    const float* __restrict__ x,
    const float* __restrict__ Wz, const float* __restrict__ Uz, const float* __restrict__ bz,
    const float* __restrict__ Wh, const float* __restrict__ Uh, const float* __restrict__ bh,
    float* __restrict__ out)
{
  // h state: [buf][m][32 x 8B]  (row = 128 bf16 = 16 x 16B units, XOR-swizzled by m&7)
  __shared__ __align__(16) unsigned long long hbuf[2][16][32];
  // x tile:  [buf][tt][m][4 x 16B units] (row = 32 bf16, units XOR-swizzled by m&3)
  __shared__ __align__(16) bf16x8 xbuf[2][8][16][4];

  const int tid  = threadIdx.x;
  const int lane = tid & 63;
  const int w    = tid >> 6;     // wave id 0..3
  const int ml   = lane & 15;    // batch row within tile (B-operand col / D col)
  const int g    = lane >> 4;    // k-group / reg-group
  const int rb   = blockIdx.x * 16;

  // ---- persistent weight fragments (registers) ----
  bf16x8 ufrag[2][2][4];   // [gate][mt][kt]
  bf16x8 wfrag[2][2];      // [gate][mt]
  f32x4  bias[2][2];       // [gate][mt] in D layout
  {
    const float* Ug[2] = {Uz, Uh};
    const float* Wg[2] = {Wz, Wh};
    const float* bg[2] = {bz, bh};
#pragma unroll
    for (int gate = 0; gate < 2; ++gate) {
#pragma unroll
      for (int mt = 0; mt < 2; ++mt) {
        const int n = 32 * w + 16 * mt + ml;   // A'-operand row index = hidden col n
#pragma unroll
        for (int kt = 0; kt < 4; ++kt) {
#pragma unroll
          for (int j = 0; j < 8; ++j)
            ufrag[gate][mt][kt][j] = (__bf16)Ug[gate][(32 * kt + 8 * g + j) * NH + n];
        }
#pragma unroll
        for (int j = 0; j < 8; ++j)
          wfrag[gate][mt][j] = (__bf16)Wg[gate][(8 * g + j) * NH + n];
        const int nb = 32 * w + 16 * mt + 4 * g;
#pragma unroll
        for (int r = 0; r < 4; ++r)
          bias[gate][mt][r] = bg[gate][nb + r];
      }
    }
  }

  // zero h state (h0 = 0)
  for (int i = tid; i < 16 * 32; i += 256) hbuf[0][i >> 5][i & 31] = 0ULL;

  // ---- x staging assignment: thread (r_st, c16) handles 16 floats of row r_st per chunk ----
  const int r_st  = tid >> 4;
  const int c16   = tid & 15;
  const int tt_st = c16 >> 1;
  const int gb_st = (c16 & 1) * 2;
  const int sw_st = r_st & 3;
  const float* xbase = x + (size_t)(rb + r_st) * (NS * NI) + c16 * 16;

  // prologue: stage chunk 0 into xbuf[0]
  {
    const float* p = xbase;
    f32x4 a0 = *(const f32x4*)(p + 0);
    f32x4 a1 = *(const f32x4*)(p + 4);
    f32x4 a2 = *(const f32x4*)(p + 8);
    f32x4 a3 = *(const f32x4*)(p + 12);
    bf16x8 u0, u1;
#pragma unroll
    for (int j = 0; j < 4; ++j) {
      u0[j]     = (__bf16)a0[j];
      u0[4 + j] = (__bf16)a1[j];
      u1[j]     = (__bf16)a2[j];
      u1[4 + j] = (__bf16)a3[j];
    }
    xbuf[0][tt_st][r_st][(gb_st + 0) ^ sw_st] = u0;
    xbuf[0][tt_st][r_st][(gb_st + 1) ^ sw_st] = u1;
  }

  __syncthreads();

  // per-lane LDS index constants
  const int sw7  = ml & 7;
  const int xidx = g ^ (ml & 3);
  int ridx[4];
#pragma unroll
  for (int kt = 0; kt < 4; ++kt) ridx[kt] = 2 * ((4 * kt + g) ^ sw7);
  const int widx0 = 2 * (((4 * w + 0) + (g >> 1)) ^ sw7) + (g & 1);
  const int widx1 = 2 * (((4 * w + 2) + (g >> 1)) ^ sw7) + (g & 1);

  f32x4 h0v = {0.f, 0.f, 0.f, 0.f};   // h_elem, mt = 0
  f32x4 h1v = {0.f, 0.f, 0.f, 0.f};   // h_elem, mt = 1
  const size_t obase = ((size_t)(rb + ml) * NS) * NH + 32 * w + 4 * g;

  f32x4 vx0, vx1, vx2, vx3;           // x prefetch registers

  const float NL2E  = -1.4426950408889634f;  // -log2(e)
  const float P2L2E =  2.8853900817779268f;  //  2*log2(e)

  for (int chunk = 0; chunk < NS / 8; ++chunk) {
    const int  xb   = chunk & 1;
    const bool more = (chunk + 1 < NS / 8);
#pragma unroll
    for (int tt = 0; tt < 8; ++tt) {
      const int t = chunk * 8 + tt;

      if (tt == 0 && more) {  // issue next chunk's x loads early (latency hidden under 8 steps)
        const float* p = xbase + (size_t)(chunk + 1) * (8 * NI);
        vx0 = *(const f32x4*)(p + 0);
        vx1 = *(const f32x4*)(p + 4);
        vx2 = *(const f32x4*)(p + 8);
        vx3 = *(const f32x4*)(p + 12);
      }

      // fragments from LDS
      const bf16x8 xfrag = xbuf[xb][tt][ml][xidx];
      const int hc = t & 1;
      const unsigned long long* hrow = &hbuf[hc][ml][0];
      bf16x8 hf[4];
#pragma unroll
      for (int kt = 0; kt < 4; ++kt) hf[kt] = *(const bf16x8*)(hrow + ridx[kt]);

      // accumulate: bias + x@W + h@U
      f32x4 az0 = bias[0][0], az1 = bias[0][1];
      f32x4 ah0 = bias[1][0], ah1 = bias[1][1];
      az0 = __builtin_amdgcn_mfma_f32_16x16x32_bf16(wfrag[0][0], xfrag, az0, 0, 0, 0);
      az1 = __builtin_amdgcn_mfma_f32_16x16x32_bf16(wfrag[0][1], xfrag, az1, 0, 0, 0);
      ah0 = __builtin_amdgcn_mfma_f32_16x16x32_bf16(wfrag[1][0], xfrag, ah0, 0, 0, 0);
      ah1 = __builtin_amdgcn_mfma_f32_16x16x32_bf16(wfrag[1][1], xfrag, ah1, 0, 0, 0);
#pragma unroll
      for (int kt = 0; kt < 4; ++kt) {
        az0 = __builtin_amdgcn_mfma_f32_16x16x32_bf16(ufrag[0][0][kt], hf[kt], az0, 0, 0, 0);
        az1 = __builtin_amdgcn_mfma_f32_16x16x32_bf16(ufrag[0][1][kt], hf[kt], az1, 0, 0, 0);
        ah0 = __builtin_amdgcn_mfma_f32_16x16x32_bf16(ufrag[1][0][kt], hf[kt], ah0, 0, 0, 0);
        ah1 = __builtin_amdgcn_mfma_f32_16x16x32_bf16(ufrag[1][1][kt], hf[kt], ah1, 0, 0, 0);
      }

      // z = sigmoid(az); hh = tanh(ah); h = h + z*(hh - h)
      f32x4 hn0, hn1;
#pragma unroll
      for (int r = 0; r < 4; ++r) {
        {
          float ez = __expf(-az0[r]);   // maps to v_exp_f32
          float z  = __builtin_amdgcn_rcpf(1.f + ez);
          float eh = __builtin_amdgcn_exp2f(ah0[r] * P2L2E);
          float th = 1.f - 2.f * __builtin_amdgcn_rcpf(1.f + eh);
          hn0[r] = __builtin_fmaf(z, th - h0v[r], h0v[r]);
        }
        {
          float ez = __expf(-az1[r]);
          float z  = __builtin_amdgcn_rcpf(1.f + ez);
          float eh = __builtin_amdgcn_exp2f(ah1[r] * P2L2E);
          float th = 1.f - 2.f * __builtin_amdgcn_rcpf(1.f + eh);
          hn1[r] = __builtin_fmaf(z, th - h1v[r], h1v[r]);
        }
      }
      h0v = hn0; h1v = hn1;

      // stream hidden_seq[b, t, :]
      __builtin_nontemporal_store(hn0, (f32x4*)(out + obase + (size_t)t * NH));
      __builtin_nontemporal_store(hn1, (f32x4*)(out + obase + (size_t)t * NH + 16));

      // publish bf16 h for next step
      unsigned long long* wrow = &hbuf[hc ^ 1][ml][0];
      wrow[widx0] = pack4_bf16(hn0);
      wrow[widx1] = pack4_bf16(hn1);

      if (tt == 6 && more) {  // convert + write next x chunk into the other buffer
        bf16x8 u0, u1;
#pragma unroll
        for (int j = 0; j < 4; ++j) {
          u0[j]     = (__bf16)vx0[j];
          u0[4 + j] = (__bf16)vx1[j];
          u1[j]     = (__bf16)vx2[j];
          u1[4 + j] = (__bf16)vx3[j];
        }
        xbuf[xb ^ 1][tt_st][r_st][(gb_st + 0) ^ sw_st] = u0;
        xbuf[xb ^ 1][tt_st][r_st][(gb_st + 1) ^ sw_st] = u1;
      }

      __syncthreads();
    }
  }

  // h_last -> out[B*S*H + b*H + n]
  const size_t lbase = (size_t)NB * NS * NH + (size_t)(rb + ml) * NH + 32 * w + 4 * g;
  *(f32x4*)(out + lbase)      = h0v;
  *(f32x4*)(out + lbase + 16) = h1v;
}

extern "C" void kernel_launch(void* const* d_in, const int* in_sizes, int n_in,
                              void* d_out, int out_size, void* d_ws, size_t ws_size,
                              hipStream_t stream) {
  const float* x  = (const float*)d_in[0];
  // d_in[1..3] = W_r, U_r, b_r: unused (r gate has no effect on the output)
  const float* Wz = (const float*)d_in[4];
  const float* Uz = (const float*)d_in[5];
  const float* bz = (const float*)d_in[6];
  const float* Wh = (const float*)d_in[7];
  const float* Uh = (const float*)d_in[8];
  const float* bh = (const float*)d_in[9];
  float* out = (float*)d_out;

  gru_scan<<<dim3(NB / 16), dim3(256), 0, stream>>>(x, Wz, Uz, bz, Wh, Uh, bh, out);
}

// Round 2
// 516.515 us; speedup vs baseline: 1.1556x; 1.1556x over previous
//
#include <hip/hip_runtime.h>
#include <hip/hip_bf16.h>

typedef __bf16 bf16x8 __attribute__((ext_vector_type(8)));
typedef float  f32x4  __attribute__((ext_vector_type(4)));
typedef unsigned long long u64;

#define NB 1024
#define NS 1024
#define NI 32
#define NH 128

__device__ __forceinline__ u64 pack4_bf16(f32x4 v) {
  u64 p = 0;
#pragma unroll
  for (int r = 0; r < 4; ++r) {
    __bf16 b = (__bf16)v[r];
    unsigned short s = __builtin_bit_cast(unsigned short, b);
    p |= (u64)s << (16 * r);
  }
  return p;
}

// Block: 512 threads = 8 waves (2 per SIMD). Block owns 16 batch rows for the whole scan.
// Wave w computes hidden cols [16w, 16w+16).
// MFMA: D'[n][m] = sum_k U[k][n] * h[m][k]  (A' = U^T slice, B' = h^T)
//   B'-frag: lane l holds h[m=l&15][k = 32kt + 8(l>>4) + j]   (one ds_read_b128)
//   D'     : lane l holds h_new[m=l&15][n = 16w + 4(l>>4) + r]
// h ping-pongs in LDS as bf16, u64 units swizzled by unit ^ ((row&7)<<1).
__global__ __launch_bounds__(512, 2) void gru_scan(
    const float* __restrict__ x,
    const float* __restrict__ Wz, const float* __restrict__ Uz, const float* __restrict__ bz,
    const float* __restrict__ Wh, const float* __restrict__ Uh, const float* __restrict__ bh,
    float* __restrict__ out)
{
  __shared__ __align__(16) u64    hbuf[2][16][32];       // 8 KB  (row = 128 bf16 = 32 u64 units)
  __shared__ __align__(16) bf16x8 xbuf[2][8][16][4];     // 16 KB (row = 32 bf16 = 4 x16B units)

  const int tid  = threadIdx.x;
  const int lane = tid & 63;
  const int w    = tid >> 6;     // wave 0..7
  const int ml   = lane & 15;    // batch row in tile
  const int g    = lane >> 4;    // k-group / reg-group
  const int rb   = blockIdx.x * 16;

  // ---- persistent weight fragments ----
  bf16x8 ufrag[2][4];   // [gate][kt]
  bf16x8 wfrag[2];      // [gate]
  f32x4  bias2[2];      // [gate], D layout
  {
    const float* Ug[2] = {Uz, Uh};
    const float* Wg[2] = {Wz, Wh};
    const float* bg[2] = {bz, bh};
    const int n0 = 16 * w + ml;   // A'-row = hidden col
#pragma unroll
    for (int gate = 0; gate < 2; ++gate) {
#pragma unroll
      for (int kt = 0; kt < 4; ++kt)
#pragma unroll
        for (int j = 0; j < 8; ++j)
          ufrag[gate][kt][j] = (__bf16)Ug[gate][(32 * kt + 8 * g + j) * NH + n0];
#pragma unroll
      for (int j = 0; j < 8; ++j)
        wfrag[gate][j] = (__bf16)Wg[gate][(8 * g + j) * NH + n0];
      const int nb = 16 * w + 4 * g;
#pragma unroll
      for (int r = 0; r < 4; ++r) bias2[gate][r] = bg[gate][nb + r];
    }
  }

  // h0 = 0
  for (int i = tid; i < 16 * 32; i += 512) hbuf[0][i >> 5][i & 31] = 0ULL;

  // ---- x staging: thread (r_st, c8) handles 8 consecutive floats (one 16B bf16 unit) ----
  const int r_st  = tid >> 5;          // 0..15
  const int c8    = tid & 31;          // 0..31 -> step tt = c8>>2, unit = c8&3
  const int tt_st = c8 >> 2;
  const int un_st = (c8 & 3) ^ (r_st & 3);
  const float* xbase = x + (size_t)(rb + r_st) * (NS * NI) + c8 * 8;

  {  // stage chunk 0
    f32x4 a0 = *(const f32x4*)(xbase);
    f32x4 a1 = *(const f32x4*)(xbase + 4);
    bf16x8 u;
#pragma unroll
    for (int j = 0; j < 4; ++j) { u[j] = (__bf16)a0[j]; u[4 + j] = (__bf16)a1[j]; }
    xbuf[0][tt_st][r_st][un_st] = u;
  }
  __syncthreads();

  // per-lane LDS constants
  const int sw = (ml & 7) << 1;
  int ridx[4];
#pragma unroll
  for (int kt = 0; kt < 4; ++kt) ridx[kt] = (8 * kt + 2 * g) ^ sw;  // even -> b128 ok
  const int widx = (4 * w + g) ^ sw;
  const int xidx = g ^ (ml & 3);

  f32x4 hv = {0.f, 0.f, 0.f, 0.f};
  const size_t obase = (size_t)(rb + ml) * NS * NH + 16 * w + 4 * g;

  f32x4 vxa, vxb;  // x prefetch
  const float NL2E  = -1.4426950408889634f;  // -log2(e)
  const float P2L2E =  2.8853900817779268f;  //  2*log2(e)
  const f32x4 zero4 = {0.f, 0.f, 0.f, 0.f};

  // ax (= bias + x@W) for t = 0, computed up front
  f32x4 axz, axh;
  {
    bf16x8 xf = xbuf[0][0][ml][xidx];
    axz = __builtin_amdgcn_mfma_f32_16x16x32_bf16(wfrag[0], xf, bias2[0], 0, 0, 0);
    axh = __builtin_amdgcn_mfma_f32_16x16x32_bf16(wfrag[1], xf, bias2[1], 0, 0, 0);
  }

  for (int chunk = 0; chunk < NS / 8; ++chunk) {
    const int  xb   = chunk & 1;
    const bool more = (chunk + 1 < NS / 8);
#pragma unroll
    for (int tt = 0; tt < 8; ++tt) {
      const int t = chunk * 8 + tt;

      if (tt == 0 && more) {  // issue next chunk's x loads (covered by ~6 steps)
        const float* p = xbase + (size_t)(chunk + 1) * (8 * NI);
        vxa = *(const f32x4*)(p);
        vxb = *(const f32x4*)(p + 4);
      }

      // h-dependent part: 8 MFMAs in 4 independent chains of 2
      const u64* hrow = &hbuf[t & 1][ml][0];
      bf16x8 hf0 = *(const bf16x8*)(hrow + ridx[0]);
      bf16x8 hf1 = *(const bf16x8*)(hrow + ridx[1]);
      bf16x8 hf2 = *(const bf16x8*)(hrow + ridx[2]);
      bf16x8 hf3 = *(const bf16x8*)(hrow + ridx[3]);

      f32x4 z1 = __builtin_amdgcn_mfma_f32_16x16x32_bf16(ufrag[0][0], hf0, axz,   0, 0, 0);
      f32x4 h1 = __builtin_amdgcn_mfma_f32_16x16x32_bf16(ufrag[1][0], hf0, axh,   0, 0, 0);
      f32x4 z2 = __builtin_amdgcn_mfma_f32_16x16x32_bf16(ufrag[0][2], hf2, zero4, 0, 0, 0);
      f32x4 h2 = __builtin_amdgcn_mfma_f32_16x16x32_bf16(ufrag[1][2], hf2, zero4, 0, 0, 0);
      z1 = __builtin_amdgcn_mfma_f32_16x16x32_bf16(ufrag[0][1], hf1, z1, 0, 0, 0);
      h1 = __builtin_amdgcn_mfma_f32_16x16x32_bf16(ufrag[1][1], hf1, h1, 0, 0, 0);
      z2 = __builtin_amdgcn_mfma_f32_16x16x32_bf16(ufrag[0][3], hf3, z2, 0, 0, 0);
      h2 = __builtin_amdgcn_mfma_f32_16x16x32_bf16(ufrag[1][3], hf3, h2, 0, 0, 0);

      const f32x4 az = z1 + z2;
      const f32x4 ah = h1 + h2;

      // z = sigmoid(az); hh = tanh(ah); h = h + z*(hh - h)
      f32x4 hn;
#pragma unroll
      for (int r = 0; r < 4; ++r) {
        float ez = __builtin_amdgcn_exp2f(az[r] * NL2E);
        float zz = __builtin_amdgcn_rcpf(1.f + ez);
        float eh = __builtin_amdgcn_exp2f(ah[r] * P2L2E);
        float th = 1.f - 2.f * __builtin_amdgcn_rcpf(1.f + eh);
        hn[r] = __builtin_fmaf(zz, th - hv[r], hv[r]);
      }
      hv = hn;

      __builtin_nontemporal_store(hn, (f32x4*)(out + obase + (size_t)t * NH));

      // publish bf16 h for next step (other buffer -> single barrier per step)
      hbuf[(t + 1) & 1][ml][widx] = pack4_bf16(hn);

      if (tt == 6 && more) {  // convert + write next x chunk
        bf16x8 u;
#pragma unroll
        for (int j = 0; j < 4; ++j) { u[j] = (__bf16)vxa[j]; u[4 + j] = (__bf16)vxb[j]; }
        xbuf[xb ^ 1][tt_st][r_st][un_st] = u;
      }

      // pre-barrier: h-independent ax for step t+1 (overlaps barrier wait)
      if (t + 1 < NS) {
        const int nb_  = (tt == 7) ? (xb ^ 1) : xb;
        const int ntt  = (tt + 1) & 7;
        bf16x8 xf = xbuf[nb_][ntt][ml][xidx];
        axz = __builtin_amdgcn_mfma_f32_16x16x32_bf16(wfrag[0], xf, bias2[0], 0, 0, 0);
        axh = __builtin_amdgcn_mfma_f32_16x16x32_bf16(wfrag[1], xf, bias2[1], 0, 0, 0);
      }

      __syncthreads();
    }
  }

  // h_last
  const size_t lbase = (size_t)NB * NS * NH + (size_t)(rb + ml) * NH + 16 * w + 4 * g;
  *(f32x4*)(out + lbase) = hv;
}

extern "C" void kernel_launch(void* const* d_in, const int* in_sizes, int n_in,
                              void* d_out, int out_size, void* d_ws, size_t ws_size,
                              hipStream_t stream) {
  const float* x  = (const float*)d_in[0];
  // d_in[1..3] = W_r, U_r, b_r: unused (r gate never affects the output)
  const float* Wz = (const float*)d_in[4];
  const float* Uz = (const float*)d_in[5];
  const float* bz = (const float*)d_in[6];
  const float* Wh = (const float*)d_in[7];
  const float* Uh = (const float*)d_in[8];
  const float* bh = (const float*)d_in[9];
  float* out = (float*)d_out;

  gru_scan<<<dim3(NB / 16), dim3(512), 0, stream>>>(x, Wz, Uz, bz, Wh, Uh, bh, out);
}

// Round 3
// 479.140 us; speedup vs baseline: 1.2457x; 1.0780x over previous
//
#include <hip/hip_runtime.h>
#include <hip/hip_bf16.h>

typedef __bf16 bf16x8 __attribute__((ext_vector_type(8)));
typedef float  f32x4  __attribute__((ext_vector_type(4)));
typedef unsigned short u16;
typedef unsigned short u16x4 __attribute__((ext_vector_type(4)));
typedef unsigned long long u64;

#define NB 1024
#define NS 1024
#define NI 32
#define NH 128

__device__ __forceinline__ u64 pack4_bf16(f32x4 v) {
  u16x4 p;
#pragma unroll
  for (int r = 0; r < 4; ++r)
    p[r] = __builtin_bit_cast(u16, (__bf16)v[r]);
  return __builtin_bit_cast(u64, p);
}

// Barrier that does NOT drain vmcnt: global stores stay in flight across steps.
// (__syncthreads would emit s_waitcnt vmcnt(0) -> per-step HBM-store retire stall.)
__device__ __forceinline__ void lds_barrier() {
  __builtin_amdgcn_sched_barrier(0);
  asm volatile("s_waitcnt lgkmcnt(0)" ::: "memory");
  __builtin_amdgcn_s_barrier();
  asm volatile("" ::: "memory");
  __builtin_amdgcn_sched_barrier(0);
}

// Block: 512 threads = 8 waves (2/SIMD). Block owns 16 batch rows for the whole scan.
// Wave w computes hidden cols [16w, 16w+16).
// MFMA: D'[n][m] = sum_k U[k][n] * h[m][k]  (A' = U^T slice, B' = h^T)
//   B'-frag: lane l holds h[m=l&15][k = 32kt + 8(l>>4) + j]   (one ds_read_b128)
//   D'     : lane l holds h_new[m=l&15][n = 16w + 4(l>>4) + r]
// h ping-pongs in LDS as bf16, u64 units swizzled by unit ^ ((row&7)<<1).
__global__ __launch_bounds__(512, 2) void gru_scan(
    const float* __restrict__ x,
    const float* __restrict__ Wz, const float* __restrict__ Uz, const float* __restrict__ bz,
    const float* __restrict__ Wh, const float* __restrict__ Uh, const float* __restrict__ bh,
    float* __restrict__ out)
{
  __shared__ __align__(16) u64    hbuf[2][16][32];       // 8 KB
  __shared__ __align__(16) bf16x8 xbuf[2][8][16][4];     // 16 KB

  const int tid  = threadIdx.x;
  const int lane = tid & 63;
  const int w    = tid >> 6;     // wave 0..7
  const int ml   = lane & 15;    // batch row in tile
  const int g    = lane >> 4;    // k-group / reg-group
  const int rb   = blockIdx.x * 16;

  // ---- persistent weight fragments ----
  bf16x8 ufrag[2][4];   // [gate][kt]
  bf16x8 wfrag[2];      // [gate]
  f32x4  bias2[2];      // [gate], D layout
  {
    const float* Ug[2] = {Uz, Uh};
    const float* Wg[2] = {Wz, Wh};
    const float* bg[2] = {bz, bh};
    const int n0 = 16 * w + ml;   // A'-row = hidden col
#pragma unroll
    for (int gate = 0; gate < 2; ++gate) {
#pragma unroll
      for (int kt = 0; kt < 4; ++kt)
#pragma unroll
        for (int j = 0; j < 8; ++j)
          ufrag[gate][kt][j] = (__bf16)Ug[gate][(32 * kt + 8 * g + j) * NH + n0];
#pragma unroll
      for (int j = 0; j < 8; ++j)
        wfrag[gate][j] = (__bf16)Wg[gate][(8 * g + j) * NH + n0];
      const int nb = 16 * w + 4 * g;
#pragma unroll
      for (int r = 0; r < 4; ++r) bias2[gate][r] = bg[gate][nb + r];
    }
  }

  // h0 = 0
  for (int i = tid; i < 16 * 32; i += 512) hbuf[0][i >> 5][i & 31] = 0ULL;

  // ---- x staging: thread (r_st, c8) handles 8 consecutive floats (one 16B bf16 unit) ----
  const int r_st  = tid >> 5;          // 0..15
  const int c8    = tid & 31;          // 0..31 -> step tt = c8>>2, unit = c8&3
  const int tt_st = c8 >> 2;
  const int un_st = (c8 & 3) ^ (r_st & 3);
  const float* xbase = x + (size_t)(rb + r_st) * (NS * NI) + c8 * 8;

  {  // stage chunk 0
    f32x4 a0 = *(const f32x4*)(xbase);
    f32x4 a1 = *(const f32x4*)(xbase + 4);
    bf16x8 u;
#pragma unroll
    for (int j = 0; j < 4; ++j) { u[j] = (__bf16)a0[j]; u[4 + j] = (__bf16)a1[j]; }
    xbuf[0][tt_st][r_st][un_st] = u;
  }
  __syncthreads();   // cold path: full drain is fine here

  // per-lane LDS constants
  const int sw = (ml & 7) << 1;
  int ridx[4];
#pragma unroll
  for (int kt = 0; kt < 4; ++kt) ridx[kt] = (8 * kt + 2 * g) ^ sw;  // even -> b128 ok
  const int widx = (4 * w + g) ^ sw;
  const int xidx = g ^ (ml & 3);

  f32x4 hv = {0.f, 0.f, 0.f, 0.f};
  float* optr = out + (size_t)(rb + ml) * NS * NH + 16 * w + 4 * g;

  f32x4 vxa, vxb;  // x prefetch
  const float NL2E  = -1.4426950408889634f;  // -log2(e)
  const float P2L2E =  2.8853900817779268f;  //  2*log2(e)
  const f32x4 zero4 = {0.f, 0.f, 0.f, 0.f};

  // ax (= bias + x@W) for t = 0
  f32x4 axz, axh;
  {
    bf16x8 xf = xbuf[0][0][ml][xidx];
    axz = __builtin_amdgcn_mfma_f32_16x16x32_bf16(wfrag[0], xf, bias2[0], 0, 0, 0);
    axh = __builtin_amdgcn_mfma_f32_16x16x32_bf16(wfrag[1], xf, bias2[1], 0, 0, 0);
  }

  for (int chunk = 0; chunk < NS / 8; ++chunk) {
    const int  xb   = chunk & 1;
    const bool more = (chunk + 1 < NS / 8);
#pragma unroll
    for (int tt = 0; tt < 8; ++tt) {
      const int t = chunk * 8 + tt;

      if (tt == 0 && more) {  // issue next chunk's x loads (~6 steps of cover)
        const float* p = xbase + (size_t)(chunk + 1) * (8 * NI);
        vxa = *(const f32x4*)(p);
        vxb = *(const f32x4*)(p + 4);
      }

      // h-dependent part: 8 MFMAs in 4 independent chains of 2
      const u64* hrow = &hbuf[t & 1][ml][0];
      bf16x8 hf0 = *(const bf16x8*)(hrow + ridx[0]);
      bf16x8 hf1 = *(const bf16x8*)(hrow + ridx[1]);
      bf16x8 hf2 = *(const bf16x8*)(hrow + ridx[2]);
      bf16x8 hf3 = *(const bf16x8*)(hrow + ridx[3]);

      f32x4 z1 = __builtin_amdgcn_mfma_f32_16x16x32_bf16(ufrag[0][0], hf0, axz,   0, 0, 0);
      f32x4 h1 = __builtin_amdgcn_mfma_f32_16x16x32_bf16(ufrag[1][0], hf0, axh,   0, 0, 0);
      f32x4 z2 = __builtin_amdgcn_mfma_f32_16x16x32_bf16(ufrag[0][2], hf2, zero4, 0, 0, 0);
      f32x4 h2 = __builtin_amdgcn_mfma_f32_16x16x32_bf16(ufrag[1][2], hf2, zero4, 0, 0, 0);
      z1 = __builtin_amdgcn_mfma_f32_16x16x32_bf16(ufrag[0][1], hf1, z1, 0, 0, 0);
      h1 = __builtin_amdgcn_mfma_f32_16x16x32_bf16(ufrag[1][1], hf1, h1, 0, 0, 0);
      z2 = __builtin_amdgcn_mfma_f32_16x16x32_bf16(ufrag[0][3], hf3, z2, 0, 0, 0);
      h2 = __builtin_amdgcn_mfma_f32_16x16x32_bf16(ufrag[1][3], hf3, h2, 0, 0, 0);

      const f32x4 az = z1 + z2;
      const f32x4 ah = h1 + h2;

      // z = sigmoid(az); hh = tanh(ah); h = h + z*(hh - h)
      f32x4 hn;
#pragma unroll
      for (int r = 0; r < 4; ++r) {
        float ez = __builtin_amdgcn_exp2f(az[r] * NL2E);
        float zz = __builtin_amdgcn_rcpf(1.f + ez);
        float eh = __builtin_amdgcn_exp2f(ah[r] * P2L2E);
        float th = 1.f - 2.f * __builtin_amdgcn_rcpf(1.f + eh);
        hn[r] = __builtin_fmaf(zz, th - hv[r], hv[r]);
      }
      hv = hn;

      // publish bf16 h for next step FIRST (critical for next step's ds_read)
      hbuf[(t + 1) & 1][ml][widx] = pack4_bf16(hn);

      if (tt == 6 && more) {  // convert + write next x chunk
        bf16x8 u;
#pragma unroll
        for (int j = 0; j < 4; ++j) { u[j] = (__bf16)vxa[j]; u[4 + j] = (__bf16)vxb[j]; }
        xbuf[xb ^ 1][tt_st][r_st][un_st] = u;
      }

      // pre-barrier: h-independent ax for step t+1 (branchless; last-step value unused)
      {
        const int nb_ = (tt == 7) ? (xb ^ 1) : xb;
        const int ntt = (tt + 1) & 7;
        bf16x8 xf = xbuf[nb_][ntt][ml][xidx];
        axz = __builtin_amdgcn_mfma_f32_16x16x32_bf16(wfrag[0], xf, bias2[0], 0, 0, 0);
        axh = __builtin_amdgcn_mfma_f32_16x16x32_bf16(wfrag[1], xf, bias2[1], 0, 0, 0);
      }

      // stream hidden_seq[b, t, :] — stays in flight across the barrier
      __builtin_nontemporal_store(hn, (f32x4*)optr);
      optr += NH;

      lds_barrier();   // lgkmcnt(0) + s_barrier only; no vmcnt drain
    }
  }

  // h_last
  const size_t lbase = (size_t)NB * NS * NH + (size_t)(rb + ml) * NH + 16 * w + 4 * g;
  *(f32x4*)(out + lbase) = hv;
}

extern "C" void kernel_launch(void* const* d_in, const int* in_sizes, int n_in,
                              void* d_out, int out_size, void* d_ws, size_t ws_size,
                              hipStream_t stream) {
  const float* x  = (const float*)d_in[0];
  // d_in[1..3] = W_r, U_r, b_r: unused (r gate never affects the output)
  const float* Wz = (const float*)d_in[4];
  const float* Uz = (const float*)d_in[5];
  const float* bz = (const float*)d_in[6];
  const float* Wh = (const float*)d_in[7];
  const float* Uh = (const float*)d_in[8];
  const float* bh = (const float*)d_in[9];
  float* out = (float*)d_out;

  gru_scan<<<dim3(NB / 16), dim3(512), 0, stream>>>(x, Wz, Uz, bz, Wh, Uh, bh, out);
}